// Round 17
// baseline (151.156 us; speedup 1.0000x reference)
//
#include <hip/hip_runtime.h>
#include <limits.h>

// Problem constants (fixed by the reference: LATTICE=(4096,4096), N_CLUSTERS=262144)
#define N_SITES   (4096 * 4096)      // 16,777,216
#define N_LABELS  262144
#define NWORDS    (N_SITES / 32)     // 524,288 bitmap words
#define NSEENW    (N_LABELS / 32)    // 8,192 seen/flip bitmap words (32 KB)
#define WPC       256                // words per chunk
#define NCHUNKS   (NWORDS / WPC)     // 2048

// Seed: ONE blind atomicMin pass over a raster-prefix. Measured ceiling:
// scattered dword atomics ~25 G/s (32 B write-through each) -> cost =
// count * 40ns. S=640K ~ marginal-cost optimum vs flat-pass fallback.
#define SEED_TPB    256
#define SEED_BLOCKS 640
#define SEED_INT4   (SEED_BLOCKS * SEED_TPB)     // 163,840 int4 = 655,360 sites
#define ZERO_BLOCKS 512                          // zero the 2 MB bitmap

// Flat passes: persistent geometry. 512 blocks x 1024 thr = 2 resident
// blocks/CU, 32 waves/CU; LDS staged once. k_first_flat: each block owns a
// CONTIGUOUS 32K-site range and compacts fallback sites into a 24 KB LDS
// list (global ops only in the short drain phase -> streaming stays MLP).
#define FLAT_BLOCKS 512
#define FLAT_TPB    1024
#define FLAT_THREADS (FLAT_BLOCKS * FLAT_TPB)   // 524,288; n4 = 8 * this
#define BLOCK_INT4  (N_SITES / 4 / FLAT_BLOCKS) // 8,192 int4 per block
#define LIST_CAP    3072                         // mean 2.7K, 7-sigma safe

// plain ext-vector type for nontemporal builtins (HIP_vector_type is rejected)
typedef float f32x4 __attribute__((ext_vector_type(4)));

// ---------------- kernel 1: init first_idx ----------------
__global__ void k_init(int* __restrict__ first_idx) {
    int t = blockIdx.x * blockDim.x + threadIdx.x;   // N_LABELS threads
    first_idx[t] = INT_MAX;
}

// ---------------- kernel 2a: blind seed + bitmap zero ----------------
// Seed blocks: blind atomicMin over the prefix (commutative -> exact min; a
// label present in the prefix has its global first occurrence there too).
// Zero blocks: clear the 2 MB occupancy bitmap for k_scatter.
__global__ void k_seed_blind(const int4* __restrict__ lab4, int* __restrict__ first_idx,
                             uint4* __restrict__ bitmap4) {
    if (blockIdx.x < SEED_BLOCKS) {
        int t = blockIdx.x * blockDim.x + threadIdx.x;   // [0, SEED_INT4)
        int4 L = lab4[t];
        int b  = t * 4;
        atomicMin(&first_idx[L.x], b);
        atomicMin(&first_idx[L.y], b + 1);
        atomicMin(&first_idx[L.z], b + 2);
        atomicMin(&first_idx[L.w], b + 3);
    } else {
        int i = (blockIdx.x - SEED_BLOCKS) * blockDim.x + threadIdx.x;
        bitmap4[i] = make_uint4(0u, 0u, 0u, 0u);   // 131,072 uint4
    }
}

// ---------------- kernel 2b: build 32 KB 'seen' bitmap from first_idx ----------------
__global__ void k_seen(const int* __restrict__ first_idx, unsigned* __restrict__ seen) {
    int l = blockIdx.x * blockDim.x + threadIdx.x;       // N_LABELS threads
    unsigned long long m = __ballot(first_idx[l] != INT_MAX);
    int lane = threadIdx.x & 63;
    if (lane == 0)       seen[l >> 5] = (unsigned)m;
    else if (lane == 32) seen[l >> 5] = (unsigned)(m >> 32);
}

// ---------------- kernel 2c: completion pass (ballot-compaction) ----------------
// Streaming loop: label load + LDS bitmap probe + wave ballot + LDS list
// push. NO global loads/atomics in the hot loop (R15: branchy fallback
// serialized ~32 L2 round trips/thread; R16: unconditional probes thrashed
// coherence). Drain phase after syncthreads: ~3 entries/thread, filtered
// atomicMin. Blocks cover contiguous ranges in dispatch order, so later
// blocks' filters see populated values (windowed-seed effect). Overflow
// (astronomically rare) takes the direct filtered-atomic path -- exact.
__global__ void __launch_bounds__(FLAT_TPB)
k_first_flat(const int4* __restrict__ lab4, int* __restrict__ first_idx,
             const unsigned* __restrict__ seen) {
    __shared__ unsigned slds[NSEENW];        // 32 KB
    __shared__ uint2    list[LIST_CAP];      // 24 KB
    __shared__ int      lcount;
    {
        const uint4* s4 = (const uint4*)seen;
        uint4*       d4 = (uint4*)slds;
        for (int i = threadIdx.x; i < NSEENW / 4; i += blockDim.x) d4[i] = s4[i];
    }
    if (threadIdx.x == 0) lcount = 0;
    __syncthreads();
    const int blockBase = blockIdx.x * BLOCK_INT4;   // int4 units
    const int lane = threadIdx.x & 63;
    #pragma unroll
    for (int it = 0; it < 2; ++it) {
        int4 L[4];
        int  t[4];
        #pragma unroll
        for (int k = 0; k < 4; ++k) {
            t[k] = blockBase + (it * 4 + k) * FLAT_TPB + threadIdx.x;
            L[k] = lab4[t[k]];
        }
        #pragma unroll
        for (int k = 0; k < 4; ++k) {
            int lbls[4] = {L[k].x, L[k].y, L[k].z, L[k].w};
            int b = t[k] * 4;
            #pragma unroll
            for (int j = 0; j < 4; ++j) {
                int lbl = lbls[j];
                bool fb = !((slds[lbl >> 5] >> (lbl & 31)) & 1u);
                unsigned long long mask = __ballot(fb);
                if (mask) {
                    int base;
                    if (lane == 0) base = atomicAdd(&lcount, (int)__popcll(mask));
                    base = __shfl(base, 0);
                    if (fb) {
                        int pos = base + (int)__popcll(mask & ((1ull << lane) - 1ull));
                        if (pos < LIST_CAP) {
                            list[pos] = make_uint2((unsigned)lbl, (unsigned)(b + j));
                        } else {
                            int cur = first_idx[lbl];
                            if (b + j < cur) atomicMin(&first_idx[lbl], b + j);
                        }
                    }
                }
            }
        }
    }
    __syncthreads();
    int n = lcount; if (n > LIST_CAP) n = LIST_CAP;
    for (int i = threadIdx.x; i < n; i += FLAT_TPB) {
        uint2 e = list[i];
        int cur = first_idx[e.x];
        if ((int)e.y < cur) atomicMin(&first_idx[e.x], (int)e.y);
    }
}

// ---------------- kernel 3: scatter seed bits into occupancy bitmap ----------------
__global__ void k_scatter(const int* __restrict__ first_idx, unsigned* __restrict__ bitmap) {
    int l = blockIdx.x * blockDim.x + threadIdx.x;
    if (l >= N_LABELS) return;
    int fi = first_idx[l];
    if (fi != INT_MAX) atomicOr(&bitmap[fi >> 5], 1u << (fi & 31));
}

// ---------------- kernel 4: per-chunk popcount sums ----------------
__global__ void k_chunk_sums(const unsigned* __restrict__ bitmap, int* __restrict__ chunkSums) {
    __shared__ int waveSums[4];
    int w  = blockIdx.x * WPC + threadIdx.x;
    int pc = __popc(bitmap[w]);
    #pragma unroll
    for (int off = 32; off; off >>= 1) pc += __shfl_down(pc, off);
    if ((threadIdx.x & 63) == 0) waveSums[threadIdx.x >> 6] = pc;
    __syncthreads();
    if (threadIdx.x == 0)
        chunkSums[blockIdx.x] = waveSums[0] + waveSums[1] + waveSums[2] + waveSums[3];
}

// ---------------- kernel 5: fused chunk-prefix reduce + per-word prefix ----------------
__global__ void k_word_prefix(const unsigned* __restrict__ bitmap,
                              const int* __restrict__ chunkSums,
                              int* __restrict__ wordPrefix) {
    __shared__ int wsum[4];
    __shared__ int rsum[4];
    int tid = threadIdx.x, lane = tid & 63, wid = tid >> 6;
    int b = blockIdx.x;
    // chunk prefix: block-reduce chunkSums[0..b)
    int acc = 0;
    for (int i = tid; i < b; i += WPC) acc += chunkSums[i];
    #pragma unroll
    for (int off = 32; off; off >>= 1) acc += __shfl_down(acc, off);
    if (lane == 0) rsum[wid] = acc;
    // per-word popcount scan
    int w  = b * WPC + tid;
    int pc = __popc(bitmap[w]);
    int v = pc;
    #pragma unroll
    for (int off = 1; off < 64; off <<= 1) {
        int u = __shfl_up(v, off);
        if (lane >= off) v += u;
    }
    if (lane == 63) wsum[wid] = v;
    __syncthreads();
    int chunkPref = rsum[0] + rsum[1] + rsum[2] + rsum[3];
    int waveoff = 0;
    #pragma unroll
    for (int i = 0; i < 4; ++i) waveoff += (i < wid) ? wsum[i] : 0;
    wordPrefix[w] = chunkPref + waveoff + v - pc;  // global exclusive prefix
}

// ---------------- kernel 6: rank -> coin -> flip bit (ballot, NO atomics) ----------------
__global__ void k_rank_flip(const int* __restrict__ first_idx,
                            const unsigned* __restrict__ bitmap,
                            const int* __restrict__ wordPrefix,
                            const float* __restrict__ coins,
                            unsigned* __restrict__ flipbits) {
    int l = blockIdx.x * blockDim.x + threadIdx.x;   // N_LABELS threads
    int fi = first_idx[l];
    bool flip = false;
    if (fi != INT_MAX) {
        int w = fi >> 5;
        unsigned mask = (1u << (fi & 31)) - 1u;
        int rank = wordPrefix[w] + __popc(bitmap[w] & mask);
        flip = (coins[rank] >= 0.5f);
    }
    unsigned long long m = __ballot(flip);
    int lane = threadIdx.x & 63;
    if (lane == 0)       flipbits[l >> 5] = (unsigned)m;
    else if (lane == 32) flipbits[l >> 5] = (unsigned)(m >> 32);
}

// ---------------- kernel 7: apply flips (persistent, LDS table, nt streams) ----------------
__global__ void __launch_bounds__(FLAT_TPB)
k_out(const int4* __restrict__ lab4, const float* __restrict__ spins,
      const unsigned* __restrict__ flipbits, float* __restrict__ out) {
    __shared__ unsigned flds[NSEENW];
    {
        const uint4* s4 = (const uint4*)flipbits;
        uint4*       d4 = (uint4*)flds;
        for (int i = threadIdx.x; i < NSEENW / 4; i += blockDim.x) d4[i] = s4[i];
    }
    __syncthreads();
    const f32x4* sp4  = (const f32x4*)spins;
    f32x4*       out4 = (f32x4*)out;
    int base = blockIdx.x * blockDim.x + threadIdx.x;
#define FLIP1(lbl, sv) __uint_as_float(__float_as_uint(sv) ^                   \
        ((((flds[(lbl) >> 5] >> ((lbl) & 31)) & 1u)) << 31))
    #pragma unroll
    for (int it = 0; it < 2; ++it) {
        int t0 = base + it * 4 * FLAT_THREADS;
        int4  L0 = lab4[t0];
        int4  L1 = lab4[t0 + FLAT_THREADS];
        int4  L2 = lab4[t0 + 2 * FLAT_THREADS];
        int4  L3 = lab4[t0 + 3 * FLAT_THREADS];
        f32x4 s0 = __builtin_nontemporal_load(&sp4[t0]);
        f32x4 s1 = __builtin_nontemporal_load(&sp4[t0 + FLAT_THREADS]);
        f32x4 s2 = __builtin_nontemporal_load(&sp4[t0 + 2 * FLAT_THREADS]);
        f32x4 s3 = __builtin_nontemporal_load(&sp4[t0 + 3 * FLAT_THREADS]);
        f32x4 o0, o1, o2, o3;
        o0.x = FLIP1(L0.x, s0.x); o0.y = FLIP1(L0.y, s0.y);
        o0.z = FLIP1(L0.z, s0.z); o0.w = FLIP1(L0.w, s0.w);
        o1.x = FLIP1(L1.x, s1.x); o1.y = FLIP1(L1.y, s1.y);
        o1.z = FLIP1(L1.z, s1.z); o1.w = FLIP1(L1.w, s1.w);
        o2.x = FLIP1(L2.x, s2.x); o2.y = FLIP1(L2.y, s2.y);
        o2.z = FLIP1(L2.z, s2.z); o2.w = FLIP1(L2.w, s2.w);
        o3.x = FLIP1(L3.x, s3.x); o3.y = FLIP1(L3.y, s3.y);
        o3.z = FLIP1(L3.z, s3.z); o3.w = FLIP1(L3.w, s3.w);
        __builtin_nontemporal_store(o0, &out4[t0]);
        __builtin_nontemporal_store(o1, &out4[t0 + FLAT_THREADS]);
        __builtin_nontemporal_store(o2, &out4[t0 + 2 * FLAT_THREADS]);
        __builtin_nontemporal_store(o3, &out4[t0 + 3 * FLAT_THREADS]);
    }
#undef FLIP1
}

extern "C" void kernel_launch(void* const* d_in, const int* in_sizes, int n_in,
                              void* d_out, int out_size, void* d_ws, size_t ws_size,
                              hipStream_t stream) {
    const float* spins  = (const float*)d_in[0];
    const int*   labels = (const int*)d_in[1];
    const float* coins  = (const float*)d_in[2];
    float*       out    = (float*)d_out;

    // workspace layout (~5.2 MB total)
    char* ws = (char*)d_ws;
    int*      first_idx  = (int*)ws;                                   // 1 MB
    unsigned* bitmap     = (unsigned*)(ws + (1u << 20));               // 2 MB
    int*      wordPrefix = (int*)(ws + 3u * (1u << 20));               // 2 MB
    int*      chunkSums  = (int*)(ws + 5u * (1u << 20));               // 8 KB
    unsigned* seen       = (unsigned*)(ws + 5u*(1u<<20) + (1u<<15));   // 32 KB
    unsigned* flipbits   = (unsigned*)(ws + 5u*(1u<<20) + 2u*(1u<<15)); // 32 KB

    k_init<<<N_LABELS / 256, 256, 0, stream>>>(first_idx);
    k_seed_blind<<<SEED_BLOCKS + ZERO_BLOCKS, SEED_TPB, 0, stream>>>(
        (const int4*)labels, first_idx, (uint4*)bitmap);
    k_seen<<<N_LABELS / 256, 256, 0, stream>>>(first_idx, seen);
    k_first_flat<<<FLAT_BLOCKS, FLAT_TPB, 0, stream>>>((const int4*)labels, first_idx, seen);
    k_scatter<<<N_LABELS / 256, 256, 0, stream>>>(first_idx, bitmap);
    k_chunk_sums<<<NCHUNKS, WPC, 0, stream>>>(bitmap, chunkSums);
    k_word_prefix<<<NCHUNKS, WPC, 0, stream>>>(bitmap, chunkSums, wordPrefix);
    k_rank_flip<<<N_LABELS / 256, 256, 0, stream>>>(first_idx, bitmap, wordPrefix, coins, flipbits);
    k_out<<<FLAT_BLOCKS, FLAT_TPB, 0, stream>>>((const int4*)labels, (const float*)spins,
                                                flipbits, (float*)out);
}

// Round 18
// 139.914 us; speedup vs baseline: 1.0804x; 1.0804x over previous
//
#include <hip/hip_runtime.h>
#include <limits.h>

// Problem constants (fixed by the reference: LATTICE=(4096,4096), N_CLUSTERS=262144)
#define N_SITES   (4096 * 4096)      // 16,777,216
#define N_LABELS  262144
#define NWORDS    (N_SITES / 32)     // 524,288 bitmap words
#define NSEENW    (N_LABELS / 32)    // 8,192 seen/flip bitmap words (32 KB)
#define WPC       256                // words per chunk
#define NCHUNKS   (NWORDS / WPC)     // 2048

// Seed: ONE blind atomicMin pass over a raster-prefix. Measured ceiling:
// scattered dword atomics ~25 G/s (32 B write-through each) -> cost =
// count * 40ns. S=640K ~ marginal-cost optimum vs flat-pass fallback.
#define SEED_TPB    256
#define SEED_BLOCKS 640
#define SEED_INT4   (SEED_BLOCKS * SEED_TPB)     // 163,840 int4 = 655,360 sites
#define ZERO_BLOCKS 512                          // zero the 2 MB bitmap

// Flat passes: persistent geometry. 512 blocks x 1024 thr = 2 resident
// blocks/CU (32 KB LDS -> 64 KB slot), 32 waves/CU; LDS staged once.
#define FLAT_BLOCKS 512
#define FLAT_TPB    1024
#define FLAT_THREADS (FLAT_BLOCKS * FLAT_TPB)   // 524,288; n4 = 8 * this

// plain ext-vector type for nontemporal builtins (HIP_vector_type is rejected)
typedef float f32x4 __attribute__((ext_vector_type(4)));

// ---------------- kernel 1: init first_idx ----------------
__global__ void k_init(int* __restrict__ first_idx) {
    int t = blockIdx.x * blockDim.x + threadIdx.x;   // N_LABELS threads
    first_idx[t] = INT_MAX;
}

// ---------------- kernel 2a: blind seed + bitmap zero ----------------
// Seed blocks: blind atomicMin over the prefix (commutative -> exact min; a
// label present in the prefix has its global first occurrence there too).
// Zero blocks: clear the 2 MB occupancy bitmap for k_scatter.
__global__ void k_seed_blind(const int4* __restrict__ lab4, int* __restrict__ first_idx,
                             uint4* __restrict__ bitmap4) {
    if (blockIdx.x < SEED_BLOCKS) {
        int t = blockIdx.x * blockDim.x + threadIdx.x;   // [0, SEED_INT4)
        int4 L = lab4[t];
        int b  = t * 4;
        atomicMin(&first_idx[L.x], b);
        atomicMin(&first_idx[L.y], b + 1);
        atomicMin(&first_idx[L.z], b + 2);
        atomicMin(&first_idx[L.w], b + 3);
    } else {
        int i = (blockIdx.x - SEED_BLOCKS) * blockDim.x + threadIdx.x;
        bitmap4[i] = make_uint4(0u, 0u, 0u, 0u);   // 131,072 uint4
    }
}

// ---------------- kernel 2b: build 32 KB 'seen' bitmap from first_idx ----------------
__global__ void k_seen(const int* __restrict__ first_idx, unsigned* __restrict__ seen) {
    int l = blockIdx.x * blockDim.x + threadIdx.x;       // N_LABELS threads
    unsigned long long m = __ballot(first_idx[l] != INT_MAX);
    int lane = threadIdx.x & 63;
    if (lane == 0)       seen[l >> 5] = (unsigned)m;
    else if (lane == 32) seen[l >> 5] = (unsigned)(m >> 32);
}

// ---------------- kernel 2c: completion pass (persistent, phase-split MLP) ----------------
// 32 KB read-only 'seen' bitmap staged in LDS once per block. A set bit
// implies first_idx[l] already holds the exact global first index, so
// skipping is exact. Fallback (~8% of slots):
// R15 lesson: interleaved {load; atomicMin} serializes -- the compiler cannot
// hoist load j+1 above atomic j (same-array alias), so each fallback costs a
// full L2 round trip. R16/R17 lessons: unconditional loads thrash coherence;
// ballot-compaction serializes on cross-lane ops. Fix: PHASE-SPLIT -- issue
// all 16 exec-masked filter loads back-to-back (independent -> full MLP),
// THEN all filtered atomics (aliasing pins the phases in this order).
__global__ void __launch_bounds__(FLAT_TPB)
k_first_flat(const int4* __restrict__ lab4, int* __restrict__ first_idx,
             const unsigned* __restrict__ seen) {
    __shared__ unsigned slds[NSEENW];
    {
        const uint4* s4 = (const uint4*)seen;
        uint4*       d4 = (uint4*)slds;
        for (int i = threadIdx.x; i < NSEENW / 4; i += blockDim.x) d4[i] = s4[i];
    }
    __syncthreads();
    int base = blockIdx.x * blockDim.x + threadIdx.x;
    for (int it = 0; it < 2; ++it) {
        int t0 = base + it * 4 * FLAT_THREADS;
        int4 L0 = lab4[t0];
        int4 L1 = lab4[t0 + FLAT_THREADS];
        int4 L2 = lab4[t0 + 2 * FLAT_THREADS];
        int4 L3 = lab4[t0 + 3 * FLAT_THREADS];
        int lbl[16], idx[16];
        lbl[0]=L0.x;  lbl[1]=L0.y;  lbl[2]=L0.z;  lbl[3]=L0.w;
        lbl[4]=L1.x;  lbl[5]=L1.y;  lbl[6]=L1.z;  lbl[7]=L1.w;
        lbl[8]=L2.x;  lbl[9]=L2.y;  lbl[10]=L2.z; lbl[11]=L2.w;
        lbl[12]=L3.x; lbl[13]=L3.y; lbl[14]=L3.z; lbl[15]=L3.w;
        int b0 = t0 * 4, b1 = (t0 + FLAT_THREADS) * 4;
        int b2 = (t0 + 2 * FLAT_THREADS) * 4, b3 = (t0 + 3 * FLAT_THREADS) * 4;
        idx[0]=b0;  idx[1]=b0+1;  idx[2]=b0+2;  idx[3]=b0+3;
        idx[4]=b1;  idx[5]=b1+1;  idx[6]=b1+2;  idx[7]=b1+3;
        idx[8]=b2;  idx[9]=b2+1;  idx[10]=b2+2; idx[11]=b2+3;
        idx[12]=b3; idx[13]=b3+1; idx[14]=b3+2; idx[15]=b3+3;
        bool fb[16];
        #pragma unroll
        for (int j = 0; j < 16; ++j)
            fb[j] = !((slds[lbl[j] >> 5] >> (lbl[j] & 31)) & 1u);
        // phase B: independent exec-masked filter loads (no intervening mem ops)
        int cur[16];
        #pragma unroll
        for (int j = 0; j < 16; ++j)
            if (fb[j]) cur[j] = first_idx[lbl[j]];
        // phase C: filtered atomics (cannot be hoisted above the loads: alias)
        #pragma unroll
        for (int j = 0; j < 16; ++j)
            if (fb[j] && idx[j] < cur[j]) atomicMin(&first_idx[lbl[j]], idx[j]);
    }
}

// ---------------- kernel 3: scatter seed bits into occupancy bitmap ----------------
__global__ void k_scatter(const int* __restrict__ first_idx, unsigned* __restrict__ bitmap) {
    int l = blockIdx.x * blockDim.x + threadIdx.x;
    if (l >= N_LABELS) return;
    int fi = first_idx[l];
    if (fi != INT_MAX) atomicOr(&bitmap[fi >> 5], 1u << (fi & 31));
}

// ---------------- kernel 4: per-chunk popcount sums ----------------
__global__ void k_chunk_sums(const unsigned* __restrict__ bitmap, int* __restrict__ chunkSums) {
    __shared__ int waveSums[4];
    int w  = blockIdx.x * WPC + threadIdx.x;
    int pc = __popc(bitmap[w]);
    #pragma unroll
    for (int off = 32; off; off >>= 1) pc += __shfl_down(pc, off);
    if ((threadIdx.x & 63) == 0) waveSums[threadIdx.x >> 6] = pc;
    __syncthreads();
    if (threadIdx.x == 0)
        chunkSums[blockIdx.x] = waveSums[0] + waveSums[1] + waveSums[2] + waveSums[3];
}

// ---------------- kernel 5: fused chunk-prefix reduce + per-word prefix ----------------
__global__ void k_word_prefix(const unsigned* __restrict__ bitmap,
                              const int* __restrict__ chunkSums,
                              int* __restrict__ wordPrefix) {
    __shared__ int wsum[4];
    __shared__ int rsum[4];
    int tid = threadIdx.x, lane = tid & 63, wid = tid >> 6;
    int b = blockIdx.x;
    // chunk prefix: block-reduce chunkSums[0..b)
    int acc = 0;
    for (int i = tid; i < b; i += WPC) acc += chunkSums[i];
    #pragma unroll
    for (int off = 32; off; off >>= 1) acc += __shfl_down(acc, off);
    if (lane == 0) rsum[wid] = acc;
    // per-word popcount scan
    int w  = b * WPC + tid;
    int pc = __popc(bitmap[w]);
    int v = pc;
    #pragma unroll
    for (int off = 1; off < 64; off <<= 1) {
        int u = __shfl_up(v, off);
        if (lane >= off) v += u;
    }
    if (lane == 63) wsum[wid] = v;
    __syncthreads();
    int chunkPref = rsum[0] + rsum[1] + rsum[2] + rsum[3];
    int waveoff = 0;
    #pragma unroll
    for (int i = 0; i < 4; ++i) waveoff += (i < wid) ? wsum[i] : 0;
    wordPrefix[w] = chunkPref + waveoff + v - pc;  // global exclusive prefix
}

// ---------------- kernel 6: rank -> coin -> flip bit (ballot, NO atomics) ----------------
__global__ void k_rank_flip(const int* __restrict__ first_idx,
                            const unsigned* __restrict__ bitmap,
                            const int* __restrict__ wordPrefix,
                            const float* __restrict__ coins,
                            unsigned* __restrict__ flipbits) {
    int l = blockIdx.x * blockDim.x + threadIdx.x;   // N_LABELS threads
    int fi = first_idx[l];
    bool flip = false;
    if (fi != INT_MAX) {
        int w = fi >> 5;
        unsigned mask = (1u << (fi & 31)) - 1u;
        int rank = wordPrefix[w] + __popc(bitmap[w] & mask);
        flip = (coins[rank] >= 0.5f);
    }
    unsigned long long m = __ballot(flip);
    int lane = threadIdx.x & 63;
    if (lane == 0)       flipbits[l >> 5] = (unsigned)m;
    else if (lane == 32) flipbits[l >> 5] = (unsigned)(m >> 32);
}

// ---------------- kernel 7: apply flips (persistent, LDS table, nt streams) ----------------
__global__ void __launch_bounds__(FLAT_TPB)
k_out(const int4* __restrict__ lab4, const float* __restrict__ spins,
      const unsigned* __restrict__ flipbits, float* __restrict__ out) {
    __shared__ unsigned flds[NSEENW];
    {
        const uint4* s4 = (const uint4*)flipbits;
        uint4*       d4 = (uint4*)flds;
        for (int i = threadIdx.x; i < NSEENW / 4; i += blockDim.x) d4[i] = s4[i];
    }
    __syncthreads();
    const f32x4* sp4  = (const f32x4*)spins;
    f32x4*       out4 = (f32x4*)out;
    int base = blockIdx.x * blockDim.x + threadIdx.x;
#define FLIP1(lbl, sv) __uint_as_float(__float_as_uint(sv) ^                   \
        ((((flds[(lbl) >> 5] >> ((lbl) & 31)) & 1u)) << 31))
    #pragma unroll
    for (int it = 0; it < 2; ++it) {
        int t0 = base + it * 4 * FLAT_THREADS;
        int4  L0 = lab4[t0];
        int4  L1 = lab4[t0 + FLAT_THREADS];
        int4  L2 = lab4[t0 + 2 * FLAT_THREADS];
        int4  L3 = lab4[t0 + 3 * FLAT_THREADS];
        f32x4 s0 = __builtin_nontemporal_load(&sp4[t0]);
        f32x4 s1 = __builtin_nontemporal_load(&sp4[t0 + FLAT_THREADS]);
        f32x4 s2 = __builtin_nontemporal_load(&sp4[t0 + 2 * FLAT_THREADS]);
        f32x4 s3 = __builtin_nontemporal_load(&sp4[t0 + 3 * FLAT_THREADS]);
        f32x4 o0, o1, o2, o3;
        o0.x = FLIP1(L0.x, s0.x); o0.y = FLIP1(L0.y, s0.y);
        o0.z = FLIP1(L0.z, s0.z); o0.w = FLIP1(L0.w, s0.w);
        o1.x = FLIP1(L1.x, s1.x); o1.y = FLIP1(L1.y, s1.y);
        o1.z = FLIP1(L1.z, s1.z); o1.w = FLIP1(L1.w, s1.w);
        o2.x = FLIP1(L2.x, s2.x); o2.y = FLIP1(L2.y, s2.y);
        o2.z = FLIP1(L2.z, s2.z); o2.w = FLIP1(L2.w, s2.w);
        o3.x = FLIP1(L3.x, s3.x); o3.y = FLIP1(L3.y, s3.y);
        o3.z = FLIP1(L3.z, s3.z); o3.w = FLIP1(L3.w, s3.w);
        __builtin_nontemporal_store(o0, &out4[t0]);
        __builtin_nontemporal_store(o1, &out4[t0 + FLAT_THREADS]);
        __builtin_nontemporal_store(o2, &out4[t0 + 2 * FLAT_THREADS]);
        __builtin_nontemporal_store(o3, &out4[t0 + 3 * FLAT_THREADS]);
    }
#undef FLIP1
}

extern "C" void kernel_launch(void* const* d_in, const int* in_sizes, int n_in,
                              void* d_out, int out_size, void* d_ws, size_t ws_size,
                              hipStream_t stream) {
    const float* spins  = (const float*)d_in[0];
    const int*   labels = (const int*)d_in[1];
    const float* coins  = (const float*)d_in[2];
    float*       out    = (float*)d_out;

    // workspace layout (~5.2 MB total)
    char* ws = (char*)d_ws;
    int*      first_idx  = (int*)ws;                                   // 1 MB
    unsigned* bitmap     = (unsigned*)(ws + (1u << 20));               // 2 MB
    int*      wordPrefix = (int*)(ws + 3u * (1u << 20));               // 2 MB
    int*      chunkSums  = (int*)(ws + 5u * (1u << 20));               // 8 KB
    unsigned* seen       = (unsigned*)(ws + 5u*(1u<<20) + (1u<<15));   // 32 KB
    unsigned* flipbits   = (unsigned*)(ws + 5u*(1u<<20) + 2u*(1u<<15)); // 32 KB

    k_init<<<N_LABELS / 256, 256, 0, stream>>>(first_idx);
    k_seed_blind<<<SEED_BLOCKS + ZERO_BLOCKS, SEED_TPB, 0, stream>>>(
        (const int4*)labels, first_idx, (uint4*)bitmap);
    k_seen<<<N_LABELS / 256, 256, 0, stream>>>(first_idx, seen);
    k_first_flat<<<FLAT_BLOCKS, FLAT_TPB, 0, stream>>>((const int4*)labels, first_idx, seen);
    k_scatter<<<N_LABELS / 256, 256, 0, stream>>>(first_idx, bitmap);
    k_chunk_sums<<<NCHUNKS, WPC, 0, stream>>>(bitmap, chunkSums);
    k_word_prefix<<<NCHUNKS, WPC, 0, stream>>>(bitmap, chunkSums, wordPrefix);
    k_rank_flip<<<N_LABELS / 256, 256, 0, stream>>>(first_idx, bitmap, wordPrefix, coins, flipbits);
    k_out<<<FLAT_BLOCKS, FLAT_TPB, 0, stream>>>((const int4*)labels, (const float*)spins,
                                                flipbits, (float*)out);
}

// Round 19
// 126.344 us; speedup vs baseline: 1.1964x; 1.1074x over previous
//
#include <hip/hip_runtime.h>
#include <limits.h>

// Problem constants (fixed by the reference: LATTICE=(4096,4096), N_CLUSTERS=262144)
#define N_SITES   (4096 * 4096)      // 16,777,216
#define N_INT4    (N_SITES / 4)      // 4,194,304
#define N_LABELS  262144
#define NWORDS    (N_SITES / 32)     // 524,288 bitmap words
#define NSEENW    (N_LABELS / 32)    // 8,192 seen/flip bitmap words (32 KB)
#define WPC       256                // words per chunk
#define NCHUNKS   (NWORDS / WPC)     // 2048

// Completion strategy (R15-R18 lessons): any dependent global read of the
// live first_idx table inside the streaming pass loses (serialization /
// coherence thrash / cross-lane overhead). Instead: blind fire-and-forget
// atomicMin (commutative -> exact, no wave stall) gated ONLY by the LDS
// seen-bitmap, with a mid-pass kernel-boundary re-snapshot so pass B sees
// near-full coverage and fires ~0 atomics. Atomic law: ~40ns/atomic.
//   seed  [0, 640K)        : 655K blind atomics  (~26 us)
//   passA [640K, 4.83M)    : ~344K blind atomics (~14 us)  e^-2.5 unseen
//   passB [4.83M, 16M)     : ~0 atomics, pure stream (~12 us) e^-18 unseen
#define SEED_TPB    256
#define SEED_BLOCKS 640
#define SEED_INT4   (SEED_BLOCKS * SEED_TPB)     // 163,840 int4 = 655,360 sites
#define ZERO_BLOCKS 512                          // zero the 2 MB bitmap
#define A_END_INT4  (SEED_INT4 + 2 * 524288)     // 1,212,416 (A = 2 full sweeps)

// Flat passes: persistent geometry. 512 blocks x 1024 thr = 2 resident
// blocks/CU (32 KB LDS -> 64 KB slot), 32 waves/CU; LDS staged once.
#define FLAT_BLOCKS 512
#define FLAT_TPB    1024
#define FLAT_THREADS (FLAT_BLOCKS * FLAT_TPB)   // 524,288

// plain ext-vector type for nontemporal builtins (HIP_vector_type is rejected)
typedef float f32x4 __attribute__((ext_vector_type(4)));

// ---------------- kernel 1: init first_idx ----------------
__global__ void k_init(int* __restrict__ first_idx) {
    int t = blockIdx.x * blockDim.x + threadIdx.x;   // N_LABELS threads
    first_idx[t] = INT_MAX;
}

// ---------------- kernel 2a: blind seed + bitmap zero ----------------
__global__ void k_seed_blind(const int4* __restrict__ lab4, int* __restrict__ first_idx,
                             uint4* __restrict__ bitmap4) {
    if (blockIdx.x < SEED_BLOCKS) {
        int t = blockIdx.x * blockDim.x + threadIdx.x;   // [0, SEED_INT4)
        int4 L = lab4[t];
        int b  = t * 4;
        atomicMin(&first_idx[L.x], b);
        atomicMin(&first_idx[L.y], b + 1);
        atomicMin(&first_idx[L.z], b + 2);
        atomicMin(&first_idx[L.w], b + 3);
    } else {
        int i = (blockIdx.x - SEED_BLOCKS) * blockDim.x + threadIdx.x;
        bitmap4[i] = make_uint4(0u, 0u, 0u, 0u);   // 131,072 uint4
    }
}

// ---------------- kernel 2b: build 32 KB 'seen' bitmap from first_idx ----------------
// Run after seed (snapshot 1) and again after pass A (snapshot 2).
__global__ void k_seen(const int* __restrict__ first_idx, unsigned* __restrict__ seen) {
    int l = blockIdx.x * blockDim.x + threadIdx.x;       // N_LABELS threads
    unsigned long long m = __ballot(first_idx[l] != INT_MAX);
    int lane = threadIdx.x & 63;
    if (lane == 0)       seen[l >> 5] = (unsigned)m;
    else if (lane == 32) seen[l >> 5] = (unsigned)(m >> 32);
}

// ---------------- kernel 2c: completion pass over [start4, end4) ----------------
// LDS seen-probe; unseen -> BLIND fire-and-forget atomicMin (no dependent
// global loads in the loop). Exactness: the covered range at snapshot time is
// a raster PREFIX, so seen => first_idx final; unseen => blind min is exact.
__global__ void __launch_bounds__(FLAT_TPB)
k_complete(const int4* __restrict__ lab4, int* __restrict__ first_idx,
           const unsigned* __restrict__ seen, int start4, int end4) {
    __shared__ unsigned slds[NSEENW];
    {
        const uint4* s4 = (const uint4*)seen;
        uint4*       d4 = (uint4*)slds;
        for (int i = threadIdx.x; i < NSEENW / 4; i += blockDim.x) d4[i] = s4[i];
    }
    __syncthreads();
    const int stride = FLAT_BLOCKS * FLAT_TPB;
    for (int t = start4 + blockIdx.x * blockDim.x + threadIdx.x; t < end4; t += stride) {
        int4 L = lab4[t];
        int b  = t * 4;
        if (!((slds[L.x >> 5] >> (L.x & 31)) & 1u)) atomicMin(&first_idx[L.x], b);
        if (!((slds[L.y >> 5] >> (L.y & 31)) & 1u)) atomicMin(&first_idx[L.y], b + 1);
        if (!((slds[L.z >> 5] >> (L.z & 31)) & 1u)) atomicMin(&first_idx[L.z], b + 2);
        if (!((slds[L.w >> 5] >> (L.w & 31)) & 1u)) atomicMin(&first_idx[L.w], b + 3);
    }
}

// ---------------- kernel 3: scatter seed bits into occupancy bitmap ----------------
__global__ void k_scatter(const int* __restrict__ first_idx, unsigned* __restrict__ bitmap) {
    int l = blockIdx.x * blockDim.x + threadIdx.x;
    if (l >= N_LABELS) return;
    int fi = first_idx[l];
    if (fi != INT_MAX) atomicOr(&bitmap[fi >> 5], 1u << (fi & 31));
}

// ---------------- kernel 4: per-chunk popcount sums ----------------
__global__ void k_chunk_sums(const unsigned* __restrict__ bitmap, int* __restrict__ chunkSums) {
    __shared__ int waveSums[4];
    int w  = blockIdx.x * WPC + threadIdx.x;
    int pc = __popc(bitmap[w]);
    #pragma unroll
    for (int off = 32; off; off >>= 1) pc += __shfl_down(pc, off);
    if ((threadIdx.x & 63) == 0) waveSums[threadIdx.x >> 6] = pc;
    __syncthreads();
    if (threadIdx.x == 0)
        chunkSums[blockIdx.x] = waveSums[0] + waveSums[1] + waveSums[2] + waveSums[3];
}

// ---------------- kernel 5: fused chunk-prefix reduce + per-word prefix ----------------
__global__ void k_word_prefix(const unsigned* __restrict__ bitmap,
                              const int* __restrict__ chunkSums,
                              int* __restrict__ wordPrefix) {
    __shared__ int wsum[4];
    __shared__ int rsum[4];
    int tid = threadIdx.x, lane = tid & 63, wid = tid >> 6;
    int b = blockIdx.x;
    // chunk prefix: block-reduce chunkSums[0..b)
    int acc = 0;
    for (int i = tid; i < b; i += WPC) acc += chunkSums[i];
    #pragma unroll
    for (int off = 32; off; off >>= 1) acc += __shfl_down(acc, off);
    if (lane == 0) rsum[wid] = acc;
    // per-word popcount scan
    int w  = b * WPC + tid;
    int pc = __popc(bitmap[w]);
    int v = pc;
    #pragma unroll
    for (int off = 1; off < 64; off <<= 1) {
        int u = __shfl_up(v, off);
        if (lane >= off) v += u;
    }
    if (lane == 63) wsum[wid] = v;
    __syncthreads();
    int chunkPref = rsum[0] + rsum[1] + rsum[2] + rsum[3];
    int waveoff = 0;
    #pragma unroll
    for (int i = 0; i < 4; ++i) waveoff += (i < wid) ? wsum[i] : 0;
    wordPrefix[w] = chunkPref + waveoff + v - pc;  // global exclusive prefix
}

// ---------------- kernel 6: rank -> coin -> flip bit (ballot, NO atomics) ----------------
__global__ void k_rank_flip(const int* __restrict__ first_idx,
                            const unsigned* __restrict__ bitmap,
                            const int* __restrict__ wordPrefix,
                            const float* __restrict__ coins,
                            unsigned* __restrict__ flipbits) {
    int l = blockIdx.x * blockDim.x + threadIdx.x;   // N_LABELS threads
    int fi = first_idx[l];
    bool flip = false;
    if (fi != INT_MAX) {
        int w = fi >> 5;
        unsigned mask = (1u << (fi & 31)) - 1u;
        int rank = wordPrefix[w] + __popc(bitmap[w] & mask);
        flip = (coins[rank] >= 0.5f);
    }
    unsigned long long m = __ballot(flip);
    int lane = threadIdx.x & 63;
    if (lane == 0)       flipbits[l >> 5] = (unsigned)m;
    else if (lane == 32) flipbits[l >> 5] = (unsigned)(m >> 32);
}

// ---------------- kernel 7: apply flips (persistent, LDS table, nt streams) ----------------
__global__ void __launch_bounds__(FLAT_TPB)
k_out(const int4* __restrict__ lab4, const float* __restrict__ spins,
      const unsigned* __restrict__ flipbits, float* __restrict__ out) {
    __shared__ unsigned flds[NSEENW];
    {
        const uint4* s4 = (const uint4*)flipbits;
        uint4*       d4 = (uint4*)flds;
        for (int i = threadIdx.x; i < NSEENW / 4; i += blockDim.x) d4[i] = s4[i];
    }
    __syncthreads();
    const f32x4* sp4  = (const f32x4*)spins;
    f32x4*       out4 = (f32x4*)out;
    int base = blockIdx.x * blockDim.x + threadIdx.x;
#define FLIP1(lbl, sv) __uint_as_float(__float_as_uint(sv) ^                   \
        ((((flds[(lbl) >> 5] >> ((lbl) & 31)) & 1u)) << 31))
    #pragma unroll
    for (int it = 0; it < 2; ++it) {
        int t0 = base + it * 4 * FLAT_THREADS;
        int4  L0 = lab4[t0];
        int4  L1 = lab4[t0 + FLAT_THREADS];
        int4  L2 = lab4[t0 + 2 * FLAT_THREADS];
        int4  L3 = lab4[t0 + 3 * FLAT_THREADS];
        f32x4 s0 = __builtin_nontemporal_load(&sp4[t0]);
        f32x4 s1 = __builtin_nontemporal_load(&sp4[t0 + FLAT_THREADS]);
        f32x4 s2 = __builtin_nontemporal_load(&sp4[t0 + 2 * FLAT_THREADS]);
        f32x4 s3 = __builtin_nontemporal_load(&sp4[t0 + 3 * FLAT_THREADS]);
        f32x4 o0, o1, o2, o3;
        o0.x = FLIP1(L0.x, s0.x); o0.y = FLIP1(L0.y, s0.y);
        o0.z = FLIP1(L0.z, s0.z); o0.w = FLIP1(L0.w, s0.w);
        o1.x = FLIP1(L1.x, s1.x); o1.y = FLIP1(L1.y, s1.y);
        o1.z = FLIP1(L1.z, s1.z); o1.w = FLIP1(L1.w, s1.w);
        o2.x = FLIP1(L2.x, s2.x); o2.y = FLIP1(L2.y, s2.y);
        o2.z = FLIP1(L2.z, s2.z); o2.w = FLIP1(L2.w, s2.w);
        o3.x = FLIP1(L3.x, s3.x); o3.y = FLIP1(L3.y, s3.y);
        o3.z = FLIP1(L3.z, s3.z); o3.w = FLIP1(L3.w, s3.w);
        __builtin_nontemporal_store(o0, &out4[t0]);
        __builtin_nontemporal_store(o1, &out4[t0 + FLAT_THREADS]);
        __builtin_nontemporal_store(o2, &out4[t0 + 2 * FLAT_THREADS]);
        __builtin_nontemporal_store(o3, &out4[t0 + 3 * FLAT_THREADS]);
    }
#undef FLIP1
}

extern "C" void kernel_launch(void* const* d_in, const int* in_sizes, int n_in,
                              void* d_out, int out_size, void* d_ws, size_t ws_size,
                              hipStream_t stream) {
    const float* spins  = (const float*)d_in[0];
    const int*   labels = (const int*)d_in[1];
    const float* coins  = (const float*)d_in[2];
    float*       out    = (float*)d_out;

    // workspace layout (~5.2 MB total)
    char* ws = (char*)d_ws;
    int*      first_idx  = (int*)ws;                                   // 1 MB
    unsigned* bitmap     = (unsigned*)(ws + (1u << 20));               // 2 MB
    int*      wordPrefix = (int*)(ws + 3u * (1u << 20));               // 2 MB
    int*      chunkSums  = (int*)(ws + 5u * (1u << 20));               // 8 KB
    unsigned* seen       = (unsigned*)(ws + 5u*(1u<<20) + (1u<<15));   // 32 KB
    unsigned* flipbits   = (unsigned*)(ws + 5u*(1u<<20) + 2u*(1u<<15)); // 32 KB

    k_init<<<N_LABELS / 256, 256, 0, stream>>>(first_idx);
    k_seed_blind<<<SEED_BLOCKS + ZERO_BLOCKS, SEED_TPB, 0, stream>>>(
        (const int4*)labels, first_idx, (uint4*)bitmap);
    k_seen<<<N_LABELS / 256, 256, 0, stream>>>(first_idx, seen);
    k_complete<<<FLAT_BLOCKS, FLAT_TPB, 0, stream>>>(
        (const int4*)labels, first_idx, seen, SEED_INT4, A_END_INT4);   // pass A
    k_seen<<<N_LABELS / 256, 256, 0, stream>>>(first_idx, seen);        // re-snapshot
    k_complete<<<FLAT_BLOCKS, FLAT_TPB, 0, stream>>>(
        (const int4*)labels, first_idx, seen, A_END_INT4, N_INT4);      // pass B
    k_scatter<<<N_LABELS / 256, 256, 0, stream>>>(first_idx, bitmap);
    k_chunk_sums<<<NCHUNKS, WPC, 0, stream>>>(bitmap, chunkSums);
    k_word_prefix<<<NCHUNKS, WPC, 0, stream>>>(bitmap, chunkSums, wordPrefix);
    k_rank_flip<<<N_LABELS / 256, 256, 0, stream>>>(first_idx, bitmap, wordPrefix, coins, flipbits);
    k_out<<<FLAT_BLOCKS, FLAT_TPB, 0, stream>>>((const int4*)labels, (const float*)spins,
                                                flipbits, (float*)out);
}

// Round 20
// 113.792 us; speedup vs baseline: 1.3284x; 1.1103x over previous
//
#include <hip/hip_runtime.h>
#include <limits.h>

// Problem constants (fixed by the reference: LATTICE=(4096,4096), N_CLUSTERS=262144)
#define N_SITES   (4096 * 4096)      // 16,777,216
#define N_INT4    (N_SITES / 4)      // 4,194,304
#define N_LABELS  262144
#define NWORDS    (N_SITES / 32)     // 524,288 bitmap words
#define NSEENW    (N_LABELS / 32)    // 8,192 seen/flip bitmap words (32 KB)
#define WPC       256                // words per chunk
#define NCHUNKS   (NWORDS / WPC)     // 2048

// Completion strategy (R15-R19): blind fire-and-forget atomicMin gated only
// by an LDS seen-bitmap snapshot, re-snapshotted at a kernel boundary.
// Atomic ledger (~40ns each, ~25 G/s pipe): minimize
//   S + A*e^(-S/256K) + B*e^(-(S+A)/256K)
//   S=524K, A=1.05M: 524K + 135K + 33K ~ 692K atomics (~28 us total)
//   (R19 had S=640K, A=4.2M -> ~1.0M atomics; passA range was 4x too long)
#define SEED_TPB    256
#define SEED_BLOCKS 512
#define SEED_INT4   (SEED_BLOCKS * SEED_TPB)     // 131,072 int4 = 524,288 sites
#define ZERO_BLOCKS 512                          // zero the 2 MB bitmap
#define A_END_INT4  (SEED_INT4 + 262144)         // 393,216 int4 = 1,572,864 sites

// Flat passes: persistent geometry. 512 blocks x 1024 thr, 32 KB LDS staged once.
#define FLAT_BLOCKS 512
#define FLAT_TPB    1024
#define FLAT_THREADS (FLAT_BLOCKS * FLAT_TPB)   // 524,288

// plain ext-vector type for nontemporal builtins (HIP_vector_type is rejected)
typedef float f32x4 __attribute__((ext_vector_type(4)));

// ---------------- kernel 1: init first_idx ----------------
__global__ void k_init(int* __restrict__ first_idx) {
    int t = blockIdx.x * blockDim.x + threadIdx.x;   // N_LABELS threads
    first_idx[t] = INT_MAX;
}

// ---------------- kernel 2a: blind seed + bitmap zero ----------------
__global__ void k_seed_blind(const int4* __restrict__ lab4, int* __restrict__ first_idx,
                             uint4* __restrict__ bitmap4) {
    if (blockIdx.x < SEED_BLOCKS) {
        int t = blockIdx.x * blockDim.x + threadIdx.x;   // [0, SEED_INT4)
        int4 L = lab4[t];
        int b  = t * 4;
        atomicMin(&first_idx[L.x], b);
        atomicMin(&first_idx[L.y], b + 1);
        atomicMin(&first_idx[L.z], b + 2);
        atomicMin(&first_idx[L.w], b + 3);
    } else {
        int i = (blockIdx.x - SEED_BLOCKS) * blockDim.x + threadIdx.x;
        bitmap4[i] = make_uint4(0u, 0u, 0u, 0u);   // 131,072 uint4
    }
}

// ---------------- kernel 2b: build 32 KB 'seen' bitmap from first_idx ----------------
// Run after seed (snapshot 1) and again after pass A (snapshot 2).
__global__ void k_seen(const int* __restrict__ first_idx, unsigned* __restrict__ seen) {
    int l = blockIdx.x * blockDim.x + threadIdx.x;       // N_LABELS threads
    unsigned long long m = __ballot(first_idx[l] != INT_MAX);
    int lane = threadIdx.x & 63;
    if (lane == 0)       seen[l >> 5] = (unsigned)m;
    else if (lane == 32) seen[l >> 5] = (unsigned)(m >> 32);
}

// ---------------- kernel 2c: completion pass over [start4, end4) ----------------
// LDS seen-probe; unseen -> BLIND fire-and-forget atomicMin (no dependent
// global loads in the loop). Exactness: the covered range at snapshot time is
// a raster PREFIX, so seen => first_idx final; unseen => blind min is exact.
__global__ void __launch_bounds__(FLAT_TPB)
k_complete(const int4* __restrict__ lab4, int* __restrict__ first_idx,
           const unsigned* __restrict__ seen, int start4, int end4) {
    __shared__ unsigned slds[NSEENW];
    {
        const uint4* s4 = (const uint4*)seen;
        uint4*       d4 = (uint4*)slds;
        for (int i = threadIdx.x; i < NSEENW / 4; i += blockDim.x) d4[i] = s4[i];
    }
    __syncthreads();
    const int stride = FLAT_BLOCKS * FLAT_TPB;
    for (int t = start4 + blockIdx.x * blockDim.x + threadIdx.x; t < end4; t += stride) {
        int4 L = lab4[t];
        int b  = t * 4;
        if (!((slds[L.x >> 5] >> (L.x & 31)) & 1u)) atomicMin(&first_idx[L.x], b);
        if (!((slds[L.y >> 5] >> (L.y & 31)) & 1u)) atomicMin(&first_idx[L.y], b + 1);
        if (!((slds[L.z >> 5] >> (L.z & 31)) & 1u)) atomicMin(&first_idx[L.z], b + 2);
        if (!((slds[L.w >> 5] >> (L.w & 31)) & 1u)) atomicMin(&first_idx[L.w], b + 3);
    }
}

// ---------------- kernel 3: scatter seed bits into occupancy bitmap ----------------
__global__ void k_scatter(const int* __restrict__ first_idx, unsigned* __restrict__ bitmap) {
    int l = blockIdx.x * blockDim.x + threadIdx.x;
    if (l >= N_LABELS) return;
    int fi = first_idx[l];
    if (fi != INT_MAX) atomicOr(&bitmap[fi >> 5], 1u << (fi & 31));
}

// ---------------- kernel 4: per-chunk popcount sums ----------------
__global__ void k_chunk_sums(const unsigned* __restrict__ bitmap, int* __restrict__ chunkSums) {
    __shared__ int waveSums[4];
    int w  = blockIdx.x * WPC + threadIdx.x;
    int pc = __popc(bitmap[w]);
    #pragma unroll
    for (int off = 32; off; off >>= 1) pc += __shfl_down(pc, off);
    if ((threadIdx.x & 63) == 0) waveSums[threadIdx.x >> 6] = pc;
    __syncthreads();
    if (threadIdx.x == 0)
        chunkSums[blockIdx.x] = waveSums[0] + waveSums[1] + waveSums[2] + waveSums[3];
}

// ---------------- kernel 5: fused chunk-prefix reduce + per-word prefix ----------------
__global__ void k_word_prefix(const unsigned* __restrict__ bitmap,
                              const int* __restrict__ chunkSums,
                              int* __restrict__ wordPrefix) {
    __shared__ int wsum[4];
    __shared__ int rsum[4];
    int tid = threadIdx.x, lane = tid & 63, wid = tid >> 6;
    int b = blockIdx.x;
    // chunk prefix: block-reduce chunkSums[0..b)
    int acc = 0;
    for (int i = tid; i < b; i += WPC) acc += chunkSums[i];
    #pragma unroll
    for (int off = 32; off; off >>= 1) acc += __shfl_down(acc, off);
    if (lane == 0) rsum[wid] = acc;
    // per-word popcount scan
    int w  = b * WPC + tid;
    int pc = __popc(bitmap[w]);
    int v = pc;
    #pragma unroll
    for (int off = 1; off < 64; off <<= 1) {
        int u = __shfl_up(v, off);
        if (lane >= off) v += u;
    }
    if (lane == 63) wsum[wid] = v;
    __syncthreads();
    int chunkPref = rsum[0] + rsum[1] + rsum[2] + rsum[3];
    int waveoff = 0;
    #pragma unroll
    for (int i = 0; i < 4; ++i) waveoff += (i < wid) ? wsum[i] : 0;
    wordPrefix[w] = chunkPref + waveoff + v - pc;  // global exclusive prefix
}

// ---------------- kernel 6: rank -> coin -> flip bit (ballot, NO atomics) ----------------
__global__ void k_rank_flip(const int* __restrict__ first_idx,
                            const unsigned* __restrict__ bitmap,
                            const int* __restrict__ wordPrefix,
                            const float* __restrict__ coins,
                            unsigned* __restrict__ flipbits) {
    int l = blockIdx.x * blockDim.x + threadIdx.x;   // N_LABELS threads
    int fi = first_idx[l];
    bool flip = false;
    if (fi != INT_MAX) {
        int w = fi >> 5;
        unsigned mask = (1u << (fi & 31)) - 1u;
        int rank = wordPrefix[w] + __popc(bitmap[w] & mask);
        flip = (coins[rank] >= 0.5f);
    }
    unsigned long long m = __ballot(flip);
    int lane = threadIdx.x & 63;
    if (lane == 0)       flipbits[l >> 5] = (unsigned)m;
    else if (lane == 32) flipbits[l >> 5] = (unsigned)(m >> 32);
}

// ---------------- kernel 7: apply flips (persistent, LDS table, nt streams) ----------------
__global__ void __launch_bounds__(FLAT_TPB)
k_out(const int4* __restrict__ lab4, const float* __restrict__ spins,
      const unsigned* __restrict__ flipbits, float* __restrict__ out) {
    __shared__ unsigned flds[NSEENW];
    {
        const uint4* s4 = (const uint4*)flipbits;
        uint4*       d4 = (uint4*)flds;
        for (int i = threadIdx.x; i < NSEENW / 4; i += blockDim.x) d4[i] = s4[i];
    }
    __syncthreads();
    const f32x4* sp4  = (const f32x4*)spins;
    f32x4*       out4 = (f32x4*)out;
    int base = blockIdx.x * blockDim.x + threadIdx.x;
#define FLIP1(lbl, sv) __uint_as_float(__float_as_uint(sv) ^                   \
        ((((flds[(lbl) >> 5] >> ((lbl) & 31)) & 1u)) << 31))
    #pragma unroll
    for (int it = 0; it < 2; ++it) {
        int t0 = base + it * 4 * FLAT_THREADS;
        int4  L0 = lab4[t0];
        int4  L1 = lab4[t0 + FLAT_THREADS];
        int4  L2 = lab4[t0 + 2 * FLAT_THREADS];
        int4  L3 = lab4[t0 + 3 * FLAT_THREADS];
        f32x4 s0 = __builtin_nontemporal_load(&sp4[t0]);
        f32x4 s1 = __builtin_nontemporal_load(&sp4[t0 + FLAT_THREADS]);
        f32x4 s2 = __builtin_nontemporal_load(&sp4[t0 + 2 * FLAT_THREADS]);
        f32x4 s3 = __builtin_nontemporal_load(&sp4[t0 + 3 * FLAT_THREADS]);
        f32x4 o0, o1, o2, o3;
        o0.x = FLIP1(L0.x, s0.x); o0.y = FLIP1(L0.y, s0.y);
        o0.z = FLIP1(L0.z, s0.z); o0.w = FLIP1(L0.w, s0.w);
        o1.x = FLIP1(L1.x, s1.x); o1.y = FLIP1(L1.y, s1.y);
        o1.z = FLIP1(L1.z, s1.z); o1.w = FLIP1(L1.w, s1.w);
        o2.x = FLIP1(L2.x, s2.x); o2.y = FLIP1(L2.y, s2.y);
        o2.z = FLIP1(L2.z, s2.z); o2.w = FLIP1(L2.w, s2.w);
        o3.x = FLIP1(L3.x, s3.x); o3.y = FLIP1(L3.y, s3.y);
        o3.z = FLIP1(L3.z, s3.z); o3.w = FLIP1(L3.w, s3.w);
        __builtin_nontemporal_store(o0, &out4[t0]);
        __builtin_nontemporal_store(o1, &out4[t0 + FLAT_THREADS]);
        __builtin_nontemporal_store(o2, &out4[t0 + 2 * FLAT_THREADS]);
        __builtin_nontemporal_store(o3, &out4[t0 + 3 * FLAT_THREADS]);
    }
#undef FLIP1
}

extern "C" void kernel_launch(void* const* d_in, const int* in_sizes, int n_in,
                              void* d_out, int out_size, void* d_ws, size_t ws_size,
                              hipStream_t stream) {
    const float* spins  = (const float*)d_in[0];
    const int*   labels = (const int*)d_in[1];
    const float* coins  = (const float*)d_in[2];
    float*       out    = (float*)d_out;

    // workspace layout (~5.2 MB total)
    char* ws = (char*)d_ws;
    int*      first_idx  = (int*)ws;                                   // 1 MB
    unsigned* bitmap     = (unsigned*)(ws + (1u << 20));               // 2 MB
    int*      wordPrefix = (int*)(ws + 3u * (1u << 20));               // 2 MB
    int*      chunkSums  = (int*)(ws + 5u * (1u << 20));               // 8 KB
    unsigned* seen       = (unsigned*)(ws + 5u*(1u<<20) + (1u<<15));   // 32 KB
    unsigned* flipbits   = (unsigned*)(ws + 5u*(1u<<20) + 2u*(1u<<15)); // 32 KB

    k_init<<<N_LABELS / 256, 256, 0, stream>>>(first_idx);
    k_seed_blind<<<SEED_BLOCKS + ZERO_BLOCKS, SEED_TPB, 0, stream>>>(
        (const int4*)labels, first_idx, (uint4*)bitmap);
    k_seen<<<N_LABELS / 256, 256, 0, stream>>>(first_idx, seen);
    k_complete<<<FLAT_BLOCKS, FLAT_TPB, 0, stream>>>(
        (const int4*)labels, first_idx, seen, SEED_INT4, A_END_INT4);   // pass A
    k_seen<<<N_LABELS / 256, 256, 0, stream>>>(first_idx, seen);        // re-snapshot
    k_complete<<<FLAT_BLOCKS, FLAT_TPB, 0, stream>>>(
        (const int4*)labels, first_idx, seen, A_END_INT4, N_INT4);      // pass B
    k_scatter<<<N_LABELS / 256, 256, 0, stream>>>(first_idx, bitmap);
    k_chunk_sums<<<NCHUNKS, WPC, 0, stream>>>(bitmap, chunkSums);
    k_word_prefix<<<NCHUNKS, WPC, 0, stream>>>(bitmap, chunkSums, wordPrefix);
    k_rank_flip<<<N_LABELS / 256, 256, 0, stream>>>(first_idx, bitmap, wordPrefix, coins, flipbits);
    k_out<<<FLAT_BLOCKS, FLAT_TPB, 0, stream>>>((const int4*)labels, (const float*)spins,
                                                flipbits, (float*)out);
}